// Round 2
// baseline (274.746 us; speedup 1.0000x reference)
//
#include <hip/hip_runtime.h>

// MultiHeadAttention: B=2, S=2048, D=1024, H=16, DK=64, causal.
// Inputs fp32, output fp32, intermediates bf16.
// R12: flash7 — swapped QK^T (mfma(K,Q)) so each lane holds P at fixed q=col
//   with 4 consecutive kv per v4f. P staging becomes 2x v_cvt_pk_bf16_f32 +
//   1x ds_write_b64 per (mt,nt) [8 writes/step vs 64 b16], PV ds_read_b128
//   unchanged. Counters showed VALU-issue-bound (VALUBusy 29% vs MfmaUtil 9%,
//   ~1400 VALU cy/step mostly f2bf + scalar ds_write). 4 waves/block, 4-way
//   KV split, linear fixed-CM combine (2-round LDS tree).
// ws (56 MB, aliased): Wt 8 | Qp 8 | Kp 8 | Vt 8 | Xb 24 (Ap aliases Xb[0:8])

typedef short v8s  __attribute__((ext_vector_type(8)));
typedef short v4ss __attribute__((ext_vector_type(4)));
typedef float v4f  __attribute__((ext_vector_type(4)));
typedef unsigned int v2u __attribute__((ext_vector_type(2)));

#define S_LEN 2048
#define D_DIM 1024
#define NHEAD 16
#define DK 64
#define M_ROWS 4096

__device__ inline unsigned short f2bf(float f) {
    unsigned x;
    __builtin_memcpy(&x, &f, 4);
    unsigned r = x + 0x7fffu + ((x >> 16) & 1u);  // RNE
    return (unsigned short)(r >> 16);
}

// v_cvt_pk_bf16_f32: D.lo = bf16(lo), D.hi = bf16(hi), RNE (T12 recipe, m240)
__device__ inline unsigned cvtpk_bf16(float lo, float hi) {
    unsigned d;
    asm("v_cvt_pk_bf16_f32 %0, %1, %2" : "=v"(d) : "v"(lo), "v"(hi));
    return d;
}

__device__ inline void gload_lds16(const void* g, void* l) {
    __builtin_amdgcn_global_load_lds(
        (const __attribute__((address_space(1))) unsigned int*)g,
        (__attribute__((address_space(3))) unsigned int*)l, 16, 0, 0);
}

// ---------------------------------------------------------------------------
// fp32 -> bf16 conversion of q,k,v into Xb[3][4096][1024]. Grid (2048,3) x256.
// ---------------------------------------------------------------------------
__global__ __launch_bounds__(256) void cvt_qkv(
    const float* __restrict__ q, const float* __restrict__ k,
    const float* __restrict__ v, unsigned short* __restrict__ Xb)
{
    const int z = blockIdx.y;
    const float* X = (z == 0) ? q : (z == 1) ? k : v;
    const size_t off = ((size_t)blockIdx.x * 256 + threadIdx.x) * 8;
    float4 f0 = *(const float4*)(X + off);
    float4 f1 = *(const float4*)(X + off + 4);
    v8s p;
    p[0]=(short)f2bf(f0.x); p[1]=(short)f2bf(f0.y); p[2]=(short)f2bf(f0.z); p[3]=(short)f2bf(f0.w);
    p[4]=(short)f2bf(f1.x); p[5]=(short)f2bf(f1.y); p[6]=(short)f2bf(f1.z); p[7]=(short)f2bf(f1.w);
    *(v8s*)(Xb + (size_t)z * M_ROWS * D_DIM + off) = p;
}

// ---------------------------------------------------------------------------
// Weight transpose+cast: W fp32 [k][n] -> Wt bf16 [n][k]. Grid (16,16,4).
// ---------------------------------------------------------------------------
__global__ __launch_bounds__(256) void transpose_w(
    const float* __restrict__ W0, const float* __restrict__ W1,
    const float* __restrict__ W2, const float* __restrict__ W3,
    unsigned short* __restrict__ Wt)
{
    const int z = blockIdx.z;
    const float* W = (z == 0) ? W0 : (z == 1) ? W1 : (z == 2) ? W2 : W3;
    unsigned short* dst = Wt + (size_t)z * D_DIM * D_DIM;

    __shared__ unsigned short t[64][72];
    const int n0 = blockIdx.x * 64, k0 = blockIdx.y * 64;
    const int tid = threadIdx.x;
    const int lr = tid >> 4;
    const int lc = (tid & 15) * 4;

#pragma unroll
    for (int kk = 0; kk < 64; kk += 16) {
        float4 f = *(const float4*)(W + (size_t)(k0 + kk + lr) * D_DIM + n0 + lc);
        t[lc + 0][kk + lr] = f2bf(f.x);
        t[lc + 1][kk + lr] = f2bf(f.y);
        t[lc + 2][kk + lr] = f2bf(f.z);
        t[lc + 3][kk + lr] = f2bf(f.w);
    }
    __syncthreads();
    const int wr = tid >> 2;
    const int wc = (tid & 3) * 16;
    v8s o0, o1;
#pragma unroll
    for (int e = 0; e < 8; e++) { o0[e] = t[wr][wc + e]; o1[e] = t[wr][wc + 8 + e]; }
    *(v8s*)(dst + (size_t)(n0 + wr) * D_DIM + k0 + wc)     = o0;
    *(v8s*)(dst + (size_t)(n0 + wr) * D_DIM + k0 + wc + 8) = o1;
}

// ---------------------------------------------------------------------------
// Fused QKV projection, m97 structure. Flat grid 768, 256 thr, 128x128, BK=32.
// ---------------------------------------------------------------------------
__global__ __launch_bounds__(256) void gemm_qkv(
    const unsigned short* __restrict__ Xb,
    const unsigned short* __restrict__ Wt,
    const float* __restrict__ bq, const float* __restrict__ bk,
    const float* __restrict__ bv,
    unsigned short* __restrict__ Qp, unsigned short* __restrict__ Kp,
    unsigned short* __restrict__ Vt)
{
    const int id   = blockIdx.x;
    const int xcd  = id & 7;
    const int slot = id >> 3;          // 0..95
    const int nblk = slot & 7;
    const int mg   = (slot >> 3) & 3;
    const int z    = slot >> 5;        // 0..2
    const int mblk = mg * 8 + xcd;     // 0..31

    const unsigned short* X = Xb + (size_t)z * M_ROWS * D_DIM;
    const unsigned short* W = Wt + (size_t)z * D_DIM * D_DIM;
    const float* bias = (z == 0) ? bq : (z == 1) ? bk : bv;

    __shared__ unsigned short lds_a[128 * 32];
    __shared__ unsigned short lds_b[128 * 32];

    const int tid  = threadIdx.x;
    const int lane = tid & 63;
    const int wave = tid >> 6;
    const int wm   = wave >> 1;
    const int wn   = wave & 1;
    const int quad = lane >> 4;
    const int col  = lane & 15;
    const int m0   = mblk * 128;
    const int n0   = nblk * 128;

    v4f acc[4][4];
#pragma unroll
    for (int i = 0; i < 4; i++)
#pragma unroll
        for (int j = 0; j < 4; j++)
#pragma unroll
            for (int r = 0; r < 4; r++) acc[i][j][r] = 0.0f;

    const int srow  = wave * 16 + (lane >> 2);
    const int schk  = (lane & 3) * 8;
    unsigned short* la = lds_a + wave * 512 + lane * 8;
    unsigned short* lb = lds_b + wave * 512 + lane * 8;

    for (int k0 = 0; k0 < D_DIM; k0 += 32) {
        __syncthreads();
        gload_lds16(X + (size_t)(m0 + srow) * D_DIM + k0 + schk,        la);
        gload_lds16(X + (size_t)(m0 + 64 + srow) * D_DIM + k0 + schk,   la + 2048);
        gload_lds16(W + (size_t)(n0 + srow) * D_DIM + k0 + schk,        lb);
        gload_lds16(W + (size_t)(n0 + 64 + srow) * D_DIM + k0 + schk,   lb + 2048);
        __syncthreads();

        v8s af[4], bf[4];
#pragma unroll
        for (int mt = 0; mt < 4; mt++)
            af[mt] = *(const v8s*)(lds_a + (wm * 64 + mt * 16 + col) * 32 + quad * 8);
#pragma unroll
        for (int nt = 0; nt < 4; nt++)
            bf[nt] = *(const v8s*)(lds_b + (wn * 64 + nt * 16 + col) * 32 + quad * 8);

#pragma unroll
        for (int mt = 0; mt < 4; mt++)
#pragma unroll
            for (int nt = 0; nt < 4; nt++)
                acc[mt][nt] = __builtin_amdgcn_mfma_f32_16x16x32_bf16(
                    af[mt], bf[nt], acc[mt][nt], 0, 0, 0);
    }

    int   nn[4];
    float bvv[4];
#pragma unroll
    for (int nt = 0; nt < 4; nt++) {
        nn[nt]  = n0 + wn * 64 + nt * 16 + col;
        bvv[nt] = bias[nn[nt]];
    }

    if (z < 2) {
        unsigned short* out = (z == 0) ? Qp : Kp;
#pragma unroll
        for (int mt = 0; mt < 4; mt++) {
#pragma unroll
            for (int nt = 0; nt < 4; nt++) {
                const int h  = nn[nt] >> 6;
                const int dk = nn[nt] & 63;
#pragma unroll
                for (int r = 0; r < 4; r++) {
                    int row = m0 + wm * 64 + mt * 16 + quad * 4 + r;
                    int b   = row >> 11, t = row & 2047;
                    out[(((size_t)(b * NHEAD + h) * S_LEN) + t) * DK + dk] =
                        f2bf(acc[mt][nt][r] + bvv[nt]);
                }
            }
        }
    } else {
#pragma unroll
        for (int mt = 0; mt < 4; mt++) {
#pragma unroll
            for (int nt = 0; nt < 4; nt++) {
                const int h  = nn[nt] >> 6;
                const int dk = nn[nt] & 63;
                int row = m0 + wm * 64 + mt * 16 + quad * 4;
                int b   = row >> 11, t = row & 2047;
                v4ss pk;
#pragma unroll
                for (int r = 0; r < 4; r++) pk[r] = (short)f2bf(acc[mt][nt][r] + bvv[nt]);
                *(v4ss*)(Vt + ((size_t)(b * NHEAD + h) * DK + dk) * S_LEN + t) = pk;
            }
        }
    }
}

// ---------------------------------------------------------------------------
// Flash attention v7 — swapped QK^T, cvt_pk + b64 P staging, 4-wave KV split.
// Grid: 2048 blocks x 256 thr. xcd=i&7 owns bh in [4x,4x+4); q32 descending.
// Per lane after s = mfma(K,Q): q = col (n-dim), kv = nt*16 + quad*4 + r.
// P store: pw[q][kv] row 72-short stride; write b64 (4 kv), read b128 (8 kv).
// Deferred softmax fixed CM => partials linear; 2-round LDS combine tree.
// ---------------------------------------------------------------------------
__global__ __launch_bounds__(256) void flash7(
    const unsigned short* __restrict__ Qp,
    const unsigned short* __restrict__ Kp,
    const unsigned short* __restrict__ Vt,
    unsigned short* __restrict__ Op)
{
    // union: pw 4 waves x [32][72] shorts = 18432 B | combine 2 x 64x34 f32 = 17408 B
    __shared__ __align__(16) unsigned char smem[18432];

    const int tid  = threadIdx.x;
    const int wave = tid >> 6;
    const int lane = tid & 63;
    const int quad = lane >> 4;
    const int col  = lane & 15;

    unsigned short* pw = (unsigned short*)smem + wave * (32 * 72);

    const int i   = blockIdx.x;
    const int xcd = i & 7;
    const int j   = i >> 3;
    const int bh  = xcd * 4 + (j & 3);
    const int q32 = 63 - (j >> 2);
    const int r0  = q32 * 32;

    const unsigned short* Qh = Qp + (size_t)bh * S_LEN * DK;
    const unsigned short* Kh = Kp + (size_t)bh * S_LEN * DK;
    const unsigned short* Vh = Vt + (size_t)bh * DK * S_LEN;

    v8s qf[2][2];
#pragma unroll
    for (int mt = 0; mt < 2; mt++)
#pragma unroll
        for (int c = 0; c < 2; c++)
            qf[mt][c] = *(const v8s*)(Qh + (size_t)(r0 + mt * 16 + col) * DK + c * 32 + quad * 8);

    float lpart[2] = {0.f, 0.f};
    v4f acc_o[2][4];
#pragma unroll
    for (int mt = 0; mt < 2; mt++)
#pragma unroll
        for (int nt = 0; nt < 4; nt++)
#pragma unroll
            for (int r = 0; r < 4; r++) acc_o[mt][nt][r] = 0.0f;

    const float CS = 0.18033688f;   // 0.125*log2(e)
    const float CM = 28.8539008f;   // 20*log2(e)

    const int nsteps = (q32 >> 1) + 1;

    // preload K for this wave's first step (kv = wave*64, rows < 256 always valid)
    v8s kc[2][4];
    const int kvp = wave * 64;
#pragma unroll
    for (int c = 0; c < 2; c++)
#pragma unroll
        for (int nt = 0; nt < 4; nt++)
            kc[c][nt] = *(const v8s*)(Kh + (size_t)(kvp + nt * 16 + col) * DK + c * 32 + quad * 8);

    for (int step = wave; step < nsteps; step += 4) {
        const int kv0 = step * 64;
        const int kvn = (step + 4 < nsteps) ? kv0 + 256 : kv0;

        v8s vf[2][4];
#pragma unroll
        for (int c = 0; c < 2; c++)
#pragma unroll
            for (int nt = 0; nt < 4; nt++)
                vf[c][nt] = *(const v8s*)(Vh + (size_t)(nt * 16 + col) * S_LEN + kv0 + c * 32 + quad * 8);
        v8s kn[2][4];
#pragma unroll
        for (int c = 0; c < 2; c++)
#pragma unroll
            for (int nt = 0; nt < 4; nt++)
                kn[c][nt] = *(const v8s*)(Kh + (size_t)(kvn + nt * 16 + col) * DK + c * 32 + quad * 8);

#pragma unroll
        for (int mt = 0; mt < 2; mt++) {
            // SWAPPED operands: D[m=kv][n=q]; lane: q=col, kv=nt*16+quad*4+r
            v4f s[4];
#pragma unroll
            for (int nt = 0; nt < 4; nt++) {
#pragma unroll
                for (int r = 0; r < 4; r++) s[nt][r] = 0.0f;
#pragma unroll
                for (int c = 0; c < 2; c++)
                    s[nt] = __builtin_amdgcn_mfma_f32_16x16x32_bf16(kc[c][nt], qf[mt][c], s[nt], 0, 0, 0);
            }

            const int  rbase = r0 + mt * 16;
            const bool diag  = (kv0 + 64 > rbase);
            float lp = 0.f;
#pragma unroll
            for (int nt = 0; nt < 4; nt++) {
#pragma unroll
                for (int r = 0; r < 4; r++) {
                    float p = __builtin_amdgcn_exp2f(fmaf(s[nt][r], CS, -CM));
                    if (diag && (kv0 + nt * 16 + quad * 4 + r > rbase + col)) p = 0.0f;
                    s[nt][r] = p;
                    lp += p;
                }
            }
            lpart[mt] += lp;

            // pack 4 consecutive kv (fixed q=col) -> one ds_write_b64
#pragma unroll
            for (int nt = 0; nt < 4; nt++) {
                unsigned u0 = cvtpk_bf16(s[nt][0], s[nt][1]);
                unsigned u1 = cvtpk_bf16(s[nt][2], s[nt][3]);
                v2u w; w[0] = u0; w[1] = u1;
                *(v2u*)(pw + (mt * 16 + col) * 72 + nt * 16 + quad * 4) = w;
            }
        }

        // PV: read own wave's P rows (row q=col), 8 consecutive kv per b128
#pragma unroll
        for (int mt = 0; mt < 2; mt++) {
#pragma unroll
            for (int c = 0; c < 2; c++) {
                v8s af = *(const v8s*)(pw + (mt * 16 + col) * 72 + c * 32 + quad * 8);
#pragma unroll
                for (int nt = 0; nt < 4; nt++)
                    acc_o[mt][nt] = __builtin_amdgcn_mfma_f32_16x16x32_bf16(af, vf[c][nt], acc_o[mt][nt], 0, 0, 0);
            }
        }

#pragma unroll
        for (int c = 0; c < 2; c++)
#pragma unroll
            for (int nt = 0; nt < 4; nt++)
                kc[c][nt] = kn[c][nt];
    }

    // per-wave l: reduce across quads (kv partitions); all lanes -> l[q=col]
#pragma unroll
    for (int mt = 0; mt < 2; mt++) {
        lpart[mt] += __shfl_xor(lpart[mt], 16);
        lpart[mt] += __shfl_xor(lpart[mt], 32);
    }

    // ---- cross-wave combine (linear: fixed-max deferred softmax) ----
    float* cb0 = (float*)smem;
    float* cb1 = cb0 + 64 * 34;

    auto store_part = [&](float* dst) {
#pragma unroll
        for (int mt = 0; mt < 2; mt++)
#pragma unroll
            for (int nt = 0; nt < 4; nt++)
                *(v4f*)(dst + (mt * 4 + nt) * 4) = acc_o[mt][nt];
        dst[32] = lpart[0];
        dst[33] = lpart[1];
    };
    auto add_part = [&](const float* src) {
#pragma unroll
        for (int mt = 0; mt < 2; mt++)
#pragma unroll
            for (int nt = 0; nt < 4; nt++) {
                v4f o = *(const v4f*)(src + (mt * 4 + nt) * 4);
#pragma unroll
                for (int r = 0; r < 4; r++) acc_o[mt][nt][r] += o[r];
            }
        lpart[0] += src[32];
        lpart[1] += src[33];
    };

    __syncthreads();                      // pw use complete; smem reusable
    if (wave == 1)      store_part(cb0 + lane * 34);
    else if (wave == 3) store_part(cb1 + lane * 34);
    __syncthreads();
    if (wave == 0)      add_part(cb0 + lane * 34);
    else if (wave == 2) add_part(cb1 + lane * 34);
    __syncthreads();
    if (wave == 2)      store_part(cb0 + lane * 34);
    __syncthreads();
    if (wave == 0)      add_part(cb0 + lane * 34);
    if (wave != 0) return;

    // normalize: invert, redistribute l[q] to lanes needing rows quad*4+r
    lpart[0] = 1.0f / lpart[0];
    lpart[1] = 1.0f / lpart[1];
    float li[2][4];
#pragma unroll
    for (int mt = 0; mt < 2; mt++)
#pragma unroll
        for (int r = 0; r < 4; r++)
            li[mt][r] = __shfl(lpart[mt], quad * 4 + r);

#pragma unroll
    for (int mt = 0; mt < 2; mt++) {
#pragma unroll
        for (int nt = 0; nt < 4; nt++) {
#pragma unroll
            for (int r = 0; r < 4; r++) {
                size_t addr = ((size_t)bh * S_LEN + r0 + mt * 16 + quad * 4 + r) * DK + nt * 16 + col;
                Op[addr] = f2bf(acc_o[mt][nt][r] * li[mt][r]);
            }
        }
    }
}

// ---------------------------------------------------------------------------
// Final projection, m97 staging. Flat 512 blocks, 64x128 tiles.
// ---------------------------------------------------------------------------
__global__ __launch_bounds__(256) void gemm_out(
    const unsigned short* __restrict__ Ap,
    const unsigned short* __restrict__ Wot,
    const float* __restrict__ bo,
    float* __restrict__ out)
{
    __shared__ unsigned short lds_a[64 * 32];
    __shared__ unsigned short lds_b[128 * 32];

    const int id   = blockIdx.x;
    const int xcd  = id & 7;
    const int slot = id >> 3;
    const int nblk = slot & 7;
    const int mg   = slot >> 3;
    const int mblk = mg * 8 + xcd;   // 0..63

    const int tid  = threadIdx.x;
    const int lane = tid & 63;
    const int wave = tid >> 6;
    const int wm   = wave >> 1;
    const int wn   = wave & 1;
    const int quad = lane >> 4;
    const int col  = lane & 15;
    const int m0   = mblk * 64;
    const int n0   = nblk * 128;

    v4f acc[2][4];
#pragma unroll
    for (int i = 0; i < 2; i++)
#pragma unroll
        for (int j = 0; j < 4; j++)
#pragma unroll
            for (int r = 0; r < 4; r++) acc[i][j][r] = 0.0f;

    const int srow = wave * 16 + (lane >> 2);
    const int schk = (lane & 3) * 8;
    unsigned short* la = lds_a + wave * 512 + lane * 8;
    unsigned short* lb = lds_b + wave * 512 + lane * 8;

    const int tokA = m0 + srow;
    const int bbA  = tokA >> 11, ttA = tokA & 2047;

    for (int k0 = 0; k0 < D_DIM; k0 += 32) {
        const int h = k0 >> 6;
        const int dk = (k0 & 63) + schk;
        __syncthreads();
        gload_lds16(Ap + ((size_t)(bbA * NHEAD + h) * S_LEN + ttA) * DK + dk,  la);
        gload_lds16(Wot + (size_t)(n0 + srow) * D_DIM + k0 + schk,             lb);
        gload_lds16(Wot + (size_t)(n0 + 64 + srow) * D_DIM + k0 + schk,        lb + 2048);
        __syncthreads();

        v8s af[2], bf[4];
#pragma unroll
        for (int mt = 0; mt < 2; mt++)
            af[mt] = *(const v8s*)(lds_a + (wm * 32 + mt * 16 + col) * 32 + quad * 8);
#pragma unroll
        for (int nt = 0; nt < 4; nt++)
            bf[nt] = *(const v8s*)(lds_b + (wn * 64 + nt * 16 + col) * 32 + quad * 8);

#pragma unroll
        for (int mt = 0; mt < 2; mt++)
#pragma unroll
            for (int nt = 0; nt < 4; nt++)
                acc[mt][nt] = __builtin_amdgcn_mfma_f32_16x16x32_bf16(
                    af[mt], bf[nt], acc[mt][nt], 0, 0, 0);
    }

    float bvv[4];
    int   nn[4];
#pragma unroll
    for (int nt = 0; nt < 4; nt++) {
        nn[nt]  = n0 + wn * 64 + nt * 16 + col;
        bvv[nt] = bo[nn[nt]];
    }

#pragma unroll
    for (int mt = 0; mt < 2; mt++) {
#pragma unroll
        for (int nt = 0; nt < 4; nt++) {
#pragma unroll
            for (int r = 0; r < 4; r++) {
                int row = m0 + wm * 32 + mt * 16 + quad * 4 + r;
                out[(size_t)row * D_DIM + nn[nt]] = acc[mt][nt][r] + bvv[nt];
            }
        }
    }
}

// ---------------------------------------------------------------------------
extern "C" void kernel_launch(void* const* d_in, const int* in_sizes, int n_in,
                              void* d_out, int out_size, void* d_ws, size_t ws_size,
                              hipStream_t stream) {
    const float* q  = (const float*)d_in[0];
    const float* k  = (const float*)d_in[1];
    const float* v  = (const float*)d_in[2];
    const float* Wq = (const float*)d_in[4];
    const float* bq = (const float*)d_in[5];
    const float* Wk = (const float*)d_in[6];
    const float* bk = (const float*)d_in[7];
    const float* Wv = (const float*)d_in[8];
    const float* bv = (const float*)d_in[9];
    const float* Wo = (const float*)d_in[10];
    const float* bo = (const float*)d_in[11];
    float* out = (float*)d_out;

    unsigned short* ws = (unsigned short*)d_ws;
    const size_t WT   = (size_t)D_DIM * D_DIM;     // 1M elems
    const size_t TENS = (size_t)M_ROWS * D_DIM;    // 4M elems
    unsigned short* Wt = ws;                        // 8 MB
    unsigned short* Qp = ws + 4 * WT;               // 8 MB
    unsigned short* Kp = Qp + TENS;                 // 8 MB
    unsigned short* Vt = Kp + TENS;                 // 8 MB
    unsigned short* Xb = Vt + TENS;                 // 24 MB (3 x 8)
    unsigned short* Ap = Xb;                        // aliases Xb[z=0] (dead after gemm_qkv)

    cvt_qkv<<<dim3(2048, 3), 256, 0, stream>>>(q, k, v, Xb);
    transpose_w<<<dim3(16, 16, 4), 256, 0, stream>>>(Wq, Wk, Wv, Wo, Wt);
    gemm_qkv<<<768, 256, 0, stream>>>(Xb, Wt, bq, bk, bv, Qp, Kp, Vt);
    flash7<<<2048, 256, 0, stream>>>(Qp, Kp, Vt, Ap);
    gemm_out<<<512, 256, 0, stream>>>(Ap, Wt + 3 * WT, bo, out);
}

// Round 3
// 269.037 us; speedup vs baseline: 1.0212x; 1.0212x over previous
//
#include <hip/hip_runtime.h>

// MultiHeadAttention: B=2, S=2048, D=1024, H=16, DK=64, causal.
// Inputs fp32, output fp32, intermediates bf16.
// R13: flash8 — flash6's 2-wave even/odd schedule (known 75.6us; fully
//   resident 8 blocks/CU) + flash7's VERIFIED swapped QK^T P-pack
//   (mfma(K,Q): lane holds P[q=col][4 consecutive kv] -> 2x v_cvt_pk_bf16_f32
//   + 1x ds_write_b64 per (mt,nt)) + diag-branch hoist (causal mask VALU only
//   on the single diagonal step per q-tile; branch is wave-uniform).
//   flash7's regression was the 4-wave split (2x prologues), not the pack.
// ws (56 MB, aliased): Wt 8 | Qp 8 | Kp 8 | Vt 8 | Xb 24 (Ap aliases Xb[0:8])

typedef short v8s  __attribute__((ext_vector_type(8)));
typedef short v4ss __attribute__((ext_vector_type(4)));
typedef float v4f  __attribute__((ext_vector_type(4)));
typedef unsigned int v2u __attribute__((ext_vector_type(2)));

#define S_LEN 2048
#define D_DIM 1024
#define NHEAD 16
#define DK 64
#define M_ROWS 4096

__device__ inline unsigned short f2bf(float f) {
    unsigned x;
    __builtin_memcpy(&x, &f, 4);
    unsigned r = x + 0x7fffu + ((x >> 16) & 1u);  // RNE
    return (unsigned short)(r >> 16);
}

// v_cvt_pk_bf16_f32: D.lo = bf16(lo), D.hi = bf16(hi), RNE
__device__ inline unsigned cvtpk_bf16(float lo, float hi) {
    unsigned d;
    asm("v_cvt_pk_bf16_f32 %0, %1, %2" : "=v"(d) : "v"(lo), "v"(hi));
    return d;
}

__device__ inline void gload_lds16(const void* g, void* l) {
    __builtin_amdgcn_global_load_lds(
        (const __attribute__((address_space(1))) unsigned int*)g,
        (__attribute__((address_space(3))) unsigned int*)l, 16, 0, 0);
}

// ---------------------------------------------------------------------------
// fp32 -> bf16 conversion of q,k,v into Xb[3][4096][1024]. Grid (2048,3) x256.
// ---------------------------------------------------------------------------
__global__ __launch_bounds__(256) void cvt_qkv(
    const float* __restrict__ q, const float* __restrict__ k,
    const float* __restrict__ v, unsigned short* __restrict__ Xb)
{
    const int z = blockIdx.y;
    const float* X = (z == 0) ? q : (z == 1) ? k : v;
    const size_t off = ((size_t)blockIdx.x * 256 + threadIdx.x) * 8;
    float4 f0 = *(const float4*)(X + off);
    float4 f1 = *(const float4*)(X + off + 4);
    v8s p;
    p[0]=(short)f2bf(f0.x); p[1]=(short)f2bf(f0.y); p[2]=(short)f2bf(f0.z); p[3]=(short)f2bf(f0.w);
    p[4]=(short)f2bf(f1.x); p[5]=(short)f2bf(f1.y); p[6]=(short)f2bf(f1.z); p[7]=(short)f2bf(f1.w);
    *(v8s*)(Xb + (size_t)z * M_ROWS * D_DIM + off) = p;
}

// ---------------------------------------------------------------------------
// Weight transpose+cast: W fp32 [k][n] -> Wt bf16 [n][k]. Grid (16,16,4).
// ---------------------------------------------------------------------------
__global__ __launch_bounds__(256) void transpose_w(
    const float* __restrict__ W0, const float* __restrict__ W1,
    const float* __restrict__ W2, const float* __restrict__ W3,
    unsigned short* __restrict__ Wt)
{
    const int z = blockIdx.z;
    const float* W = (z == 0) ? W0 : (z == 1) ? W1 : (z == 2) ? W2 : W3;
    unsigned short* dst = Wt + (size_t)z * D_DIM * D_DIM;

    __shared__ unsigned short t[64][72];
    const int n0 = blockIdx.x * 64, k0 = blockIdx.y * 64;
    const int tid = threadIdx.x;
    const int lr = tid >> 4;
    const int lc = (tid & 15) * 4;

#pragma unroll
    for (int kk = 0; kk < 64; kk += 16) {
        float4 f = *(const float4*)(W + (size_t)(k0 + kk + lr) * D_DIM + n0 + lc);
        t[lc + 0][kk + lr] = f2bf(f.x);
        t[lc + 1][kk + lr] = f2bf(f.y);
        t[lc + 2][kk + lr] = f2bf(f.z);
        t[lc + 3][kk + lr] = f2bf(f.w);
    }
    __syncthreads();
    const int wr = tid >> 2;
    const int wc = (tid & 3) * 16;
    v8s o0, o1;
#pragma unroll
    for (int e = 0; e < 8; e++) { o0[e] = t[wr][wc + e]; o1[e] = t[wr][wc + 8 + e]; }
    *(v8s*)(dst + (size_t)(n0 + wr) * D_DIM + k0 + wc)     = o0;
    *(v8s*)(dst + (size_t)(n0 + wr) * D_DIM + k0 + wc + 8) = o1;
}

// ---------------------------------------------------------------------------
// Fused QKV projection, m97 structure. Flat grid 768, 256 thr, 128x128, BK=32.
// ---------------------------------------------------------------------------
__global__ __launch_bounds__(256) void gemm_qkv(
    const unsigned short* __restrict__ Xb,
    const unsigned short* __restrict__ Wt,
    const float* __restrict__ bq, const float* __restrict__ bk,
    const float* __restrict__ bv,
    unsigned short* __restrict__ Qp, unsigned short* __restrict__ Kp,
    unsigned short* __restrict__ Vt)
{
    const int id   = blockIdx.x;
    const int xcd  = id & 7;
    const int slot = id >> 3;          // 0..95
    const int nblk = slot & 7;
    const int mg   = (slot >> 3) & 3;
    const int z    = slot >> 5;        // 0..2
    const int mblk = mg * 8 + xcd;     // 0..31

    const unsigned short* X = Xb + (size_t)z * M_ROWS * D_DIM;
    const unsigned short* W = Wt + (size_t)z * D_DIM * D_DIM;
    const float* bias = (z == 0) ? bq : (z == 1) ? bk : bv;

    __shared__ unsigned short lds_a[128 * 32];
    __shared__ unsigned short lds_b[128 * 32];

    const int tid  = threadIdx.x;
    const int lane = tid & 63;
    const int wave = tid >> 6;
    const int wm   = wave >> 1;
    const int wn   = wave & 1;
    const int quad = lane >> 4;
    const int col  = lane & 15;
    const int m0   = mblk * 128;
    const int n0   = nblk * 128;

    v4f acc[4][4];
#pragma unroll
    for (int i = 0; i < 4; i++)
#pragma unroll
        for (int j = 0; j < 4; j++)
#pragma unroll
            for (int r = 0; r < 4; r++) acc[i][j][r] = 0.0f;

    const int srow  = wave * 16 + (lane >> 2);
    const int schk  = (lane & 3) * 8;
    unsigned short* la = lds_a + wave * 512 + lane * 8;
    unsigned short* lb = lds_b + wave * 512 + lane * 8;

    for (int k0 = 0; k0 < D_DIM; k0 += 32) {
        __syncthreads();
        gload_lds16(X + (size_t)(m0 + srow) * D_DIM + k0 + schk,        la);
        gload_lds16(X + (size_t)(m0 + 64 + srow) * D_DIM + k0 + schk,   la + 2048);
        gload_lds16(W + (size_t)(n0 + srow) * D_DIM + k0 + schk,        lb);
        gload_lds16(W + (size_t)(n0 + 64 + srow) * D_DIM + k0 + schk,   lb + 2048);
        __syncthreads();

        v8s af[4], bf[4];
#pragma unroll
        for (int mt = 0; mt < 4; mt++)
            af[mt] = *(const v8s*)(lds_a + (wm * 64 + mt * 16 + col) * 32 + quad * 8);
#pragma unroll
        for (int nt = 0; nt < 4; nt++)
            bf[nt] = *(const v8s*)(lds_b + (wn * 64 + nt * 16 + col) * 32 + quad * 8);

#pragma unroll
        for (int mt = 0; mt < 4; mt++)
#pragma unroll
            for (int nt = 0; nt < 4; nt++)
                acc[mt][nt] = __builtin_amdgcn_mfma_f32_16x16x32_bf16(
                    af[mt], bf[nt], acc[mt][nt], 0, 0, 0);
    }

    int   nn[4];
    float bvv[4];
#pragma unroll
    for (int nt = 0; nt < 4; nt++) {
        nn[nt]  = n0 + wn * 64 + nt * 16 + col;
        bvv[nt] = bias[nn[nt]];
    }

    if (z < 2) {
        unsigned short* out = (z == 0) ? Qp : Kp;
#pragma unroll
        for (int mt = 0; mt < 4; mt++) {
#pragma unroll
            for (int nt = 0; nt < 4; nt++) {
                const int h  = nn[nt] >> 6;
                const int dk = nn[nt] & 63;
#pragma unroll
                for (int r = 0; r < 4; r++) {
                    int row = m0 + wm * 64 + mt * 16 + quad * 4 + r;
                    int b   = row >> 11, t = row & 2047;
                    out[(((size_t)(b * NHEAD + h) * S_LEN) + t) * DK + dk] =
                        f2bf(acc[mt][nt][r] + bvv[nt]);
                }
            }
        }
    } else {
#pragma unroll
        for (int mt = 0; mt < 4; mt++) {
#pragma unroll
            for (int nt = 0; nt < 4; nt++) {
                const int h  = nn[nt] >> 6;
                const int dk = nn[nt] & 63;
                int row = m0 + wm * 64 + mt * 16 + quad * 4;
                int b   = row >> 11, t = row & 2047;
                v4ss pk;
#pragma unroll
                for (int r = 0; r < 4; r++) pk[r] = (short)f2bf(acc[mt][nt][r] + bvv[nt]);
                *(v4ss*)(Vt + ((size_t)(b * NHEAD + h) * DK + dk) * S_LEN + t) = pk;
            }
        }
    }
}

// ---------------------------------------------------------------------------
// Flash attention v8 — 2 waves/block even/odd KV steps (flash6 schedule),
// swapped QK^T P-pack (flash7 math), diag-branch hoist.
// Grid: 2048 blocks x 128 thr. Per lane after s = mfma(K,Q): q = col,
// kv = nt*16 + quad*4 + r. P store: 2x cvt_pk + ds_write_b64 into pw[q][kv]
// (72-short row stride); PV reads b128 rows q=col (unchanged pattern).
// Deferred softmax fixed CM => partials linear; single LDS combine round.
// ---------------------------------------------------------------------------
__global__ __launch_bounds__(128) void flash8(
    const unsigned short* __restrict__ Qp,
    const unsigned short* __restrict__ Kp,
    const unsigned short* __restrict__ Vt,
    unsigned short* __restrict__ Op)
{
    // union: pw 2 waves x [32][72] shorts = 9216 B | combine 64x34 f32 = 8704 B
    __shared__ __align__(16) unsigned char smem[9216];

    const int tid  = threadIdx.x;
    const int wave = tid >> 6;
    const int lane = tid & 63;
    const int quad = lane >> 4;
    const int col  = lane & 15;

    unsigned short* pw = (unsigned short*)smem + wave * (32 * 72);

    const int i   = blockIdx.x;
    const int xcd = i & 7;
    const int j   = i >> 3;
    const int bh  = xcd * 4 + (j & 3);
    const int q32 = 63 - (j >> 2);
    const int r0  = q32 * 32;

    const unsigned short* Qh = Qp + (size_t)bh * S_LEN * DK;
    const unsigned short* Kh = Kp + (size_t)bh * S_LEN * DK;
    const unsigned short* Vh = Vt + (size_t)bh * DK * S_LEN;

    v8s qf[2][2];
#pragma unroll
    for (int mt = 0; mt < 2; mt++)
#pragma unroll
        for (int c = 0; c < 2; c++)
            qf[mt][c] = *(const v8s*)(Qh + (size_t)(r0 + mt * 16 + col) * DK + c * 32 + quad * 8);

    float lpart[2] = {0.f, 0.f};
    v4f acc_o[2][4];
#pragma unroll
    for (int mt = 0; mt < 2; mt++)
#pragma unroll
        for (int nt = 0; nt < 4; nt++)
#pragma unroll
            for (int r = 0; r < 4; r++) acc_o[mt][nt][r] = 0.0f;

    const float CS = 0.18033688f;   // 0.125*log2(e)
    const float CM = 28.8539008f;   // 20*log2(e)

    const int nsteps = (q32 >> 1) + 1;

    // preload K for this wave's first step (kv = wave*64, rows < 128 always valid)
    v8s kc[2][4];
    const int kvp = wave * 64;
#pragma unroll
    for (int c = 0; c < 2; c++)
#pragma unroll
        for (int nt = 0; nt < 4; nt++)
            kc[c][nt] = *(const v8s*)(Kh + (size_t)(kvp + nt * 16 + col) * DK + c * 32 + quad * 8);

    for (int step = wave; step < nsteps; step += 2) {
        const int kv0 = step * 64;
        const int kvn = (step + 2 < nsteps) ? kv0 + 128 : kv0;

        v8s vf[2][4];
#pragma unroll
        for (int c = 0; c < 2; c++)
#pragma unroll
            for (int nt = 0; nt < 4; nt++)
                vf[c][nt] = *(const v8s*)(Vh + (size_t)(nt * 16 + col) * S_LEN + kv0 + c * 32 + quad * 8);
        v8s kn[2][4];
#pragma unroll
        for (int c = 0; c < 2; c++)
#pragma unroll
            for (int nt = 0; nt < 4; nt++)
                kn[c][nt] = *(const v8s*)(Kh + (size_t)(kvn + nt * 16 + col) * DK + c * 32 + quad * 8);

#pragma unroll
        for (int mt = 0; mt < 2; mt++) {
            // SWAPPED operands: lane holds q=col, kv = nt*16 + quad*4 + r
            v4f s[4];
#pragma unroll
            for (int nt = 0; nt < 4; nt++) {
#pragma unroll
                for (int r = 0; r < 4; r++) s[nt][r] = 0.0f;
#pragma unroll
                for (int c = 0; c < 2; c++)
                    s[nt] = __builtin_amdgcn_mfma_f32_16x16x32_bf16(kc[c][nt], qf[mt][c], s[nt], 0, 0, 0);
            }

            const int rbase = r0 + mt * 16;
            float lp = 0.f;
            if (kv0 + 64 > rbase) {
                // diagonal step: causal mask active (wave-uniform branch)
#pragma unroll
                for (int nt = 0; nt < 4; nt++) {
#pragma unroll
                    for (int r = 0; r < 4; r++) {
                        float p = __builtin_amdgcn_exp2f(fmaf(s[nt][r], CS, -CM));
                        if (kv0 + nt * 16 + quad * 4 + r > rbase + col) p = 0.0f;
                        s[nt][r] = p;
                        lp += p;
                    }
                }
            } else {
#pragma unroll
                for (int nt = 0; nt < 4; nt++) {
#pragma unroll
                    for (int r = 0; r < 4; r++) {
                        float p = __builtin_amdgcn_exp2f(fmaf(s[nt][r], CS, -CM));
                        s[nt][r] = p;
                        lp += p;
                    }
                }
            }
            lpart[mt] += lp;

            // pack 4 consecutive kv (fixed q=col) -> one ds_write_b64
#pragma unroll
            for (int nt = 0; nt < 4; nt++) {
                unsigned u0 = cvtpk_bf16(s[nt][0], s[nt][1]);
                unsigned u1 = cvtpk_bf16(s[nt][2], s[nt][3]);
                v2u w; w[0] = u0; w[1] = u1;
                *(v2u*)(pw + (mt * 16 + col) * 72 + nt * 16 + quad * 4) = w;
            }
        }

        // PV: read own wave's P rows (row q=col), 8 consecutive kv per b128
#pragma unroll
        for (int mt = 0; mt < 2; mt++) {
#pragma unroll
            for (int c = 0; c < 2; c++) {
                v8s af = *(const v8s*)(pw + (mt * 16 + col) * 72 + c * 32 + quad * 8);
#pragma unroll
                for (int nt = 0; nt < 4; nt++)
                    acc_o[mt][nt] = __builtin_amdgcn_mfma_f32_16x16x32_bf16(af, vf[c][nt], acc_o[mt][nt], 0, 0, 0);
            }
        }

#pragma unroll
        for (int c = 0; c < 2; c++)
#pragma unroll
            for (int nt = 0; nt < 4; nt++)
                kc[c][nt] = kn[c][nt];
    }

    // per-wave l: reduce across quads (kv partitions); all lanes -> l[q=col]
#pragma unroll
    for (int mt = 0; mt < 2; mt++) {
        lpart[mt] += __shfl_xor(lpart[mt], 16);
        lpart[mt] += __shfl_xor(lpart[mt], 32);
    }

    // ---- cross-wave combine (linear: fixed-max deferred softmax) ----
    float* comb = (float*)smem;
    __syncthreads();                      // pw use complete; smem reusable
    if (wave == 1) {
        float* dst = comb + lane * 34;
#pragma unroll
        for (int mt = 0; mt < 2; mt++)
#pragma unroll
            for (int nt = 0; nt < 4; nt++)
                *(v4f*)(dst + (mt * 4 + nt) * 4) = acc_o[mt][nt];
        dst[32] = lpart[0];
        dst[33] = lpart[1];
    }
    __syncthreads();
    if (wave != 0) return;

    {
        const float* src = comb + lane * 34;
#pragma unroll
        for (int mt = 0; mt < 2; mt++)
#pragma unroll
            for (int nt = 0; nt < 4; nt++) {
                v4f o = *(const v4f*)(src + (mt * 4 + nt) * 4);
#pragma unroll
                for (int r = 0; r < 4; r++) acc_o[mt][nt][r] += o[r];
            }
        lpart[0] += src[32];
        lpart[1] += src[33];
    }

    // normalize: invert, redistribute l[q=col] to lanes needing rows quad*4+r
    lpart[0] = 1.0f / lpart[0];
    lpart[1] = 1.0f / lpart[1];
    float li[2][4];
#pragma unroll
    for (int mt = 0; mt < 2; mt++)
#pragma unroll
        for (int r = 0; r < 4; r++)
            li[mt][r] = __shfl(lpart[mt], quad * 4 + r);

#pragma unroll
    for (int mt = 0; mt < 2; mt++) {
#pragma unroll
        for (int nt = 0; nt < 4; nt++) {
#pragma unroll
            for (int r = 0; r < 4; r++) {
                size_t addr = ((size_t)bh * S_LEN + r0 + mt * 16 + quad * 4 + r) * DK + nt * 16 + col;
                Op[addr] = f2bf(acc_o[mt][nt][r] * li[mt][r]);
            }
        }
    }
}

// ---------------------------------------------------------------------------
// Final projection, m97 staging. Flat 512 blocks, 64x128 tiles.
// ---------------------------------------------------------------------------
__global__ __launch_bounds__(256) void gemm_out(
    const unsigned short* __restrict__ Ap,
    const unsigned short* __restrict__ Wot,
    const float* __restrict__ bo,
    float* __restrict__ out)
{
    __shared__ unsigned short lds_a[64 * 32];
    __shared__ unsigned short lds_b[128 * 32];

    const int id   = blockIdx.x;
    const int xcd  = id & 7;
    const int slot = id >> 3;
    const int nblk = slot & 7;
    const int mg   = slot >> 3;
    const int mblk = mg * 8 + xcd;   // 0..63

    const int tid  = threadIdx.x;
    const int lane = tid & 63;
    const int wave = tid >> 6;
    const int wm   = wave >> 1;
    const int wn   = wave & 1;
    const int quad = lane >> 4;
    const int col  = lane & 15;
    const int m0   = mblk * 64;
    const int n0   = nblk * 128;

    v4f acc[2][4];
#pragma unroll
    for (int i = 0; i < 2; i++)
#pragma unroll
        for (int j = 0; j < 4; j++)
#pragma unroll
            for (int r = 0; r < 4; r++) acc[i][j][r] = 0.0f;

    const int srow = wave * 16 + (lane >> 2);
    const int schk = (lane & 3) * 8;
    unsigned short* la = lds_a + wave * 512 + lane * 8;
    unsigned short* lb = lds_b + wave * 512 + lane * 8;

    const int tokA = m0 + srow;
    const int bbA  = tokA >> 11, ttA = tokA & 2047;

    for (int k0 = 0; k0 < D_DIM; k0 += 32) {
        const int h = k0 >> 6;
        const int dk = (k0 & 63) + schk;
        __syncthreads();
        gload_lds16(Ap + ((size_t)(bbA * NHEAD + h) * S_LEN + ttA) * DK + dk,  la);
        gload_lds16(Wot + (size_t)(n0 + srow) * D_DIM + k0 + schk,             lb);
        gload_lds16(Wot + (size_t)(n0 + 64 + srow) * D_DIM + k0 + schk,        lb + 2048);
        __syncthreads();

        v8s af[2], bf[4];
#pragma unroll
        for (int mt = 0; mt < 2; mt++)
            af[mt] = *(const v8s*)(lds_a + (wm * 32 + mt * 16 + col) * 32 + quad * 8);
#pragma unroll
        for (int nt = 0; nt < 4; nt++)
            bf[nt] = *(const v8s*)(lds_b + (wn * 64 + nt * 16 + col) * 32 + quad * 8);

#pragma unroll
        for (int mt = 0; mt < 2; mt++)
#pragma unroll
            for (int nt = 0; nt < 4; nt++)
                acc[mt][nt] = __builtin_amdgcn_mfma_f32_16x16x32_bf16(
                    af[mt], bf[nt], acc[mt][nt], 0, 0, 0);
    }

    float bvv[4];
    int   nn[4];
#pragma unroll
    for (int nt = 0; nt < 4; nt++) {
        nn[nt]  = n0 + wn * 64 + nt * 16 + col;
        bvv[nt] = bo[nn[nt]];
    }

#pragma unroll
    for (int mt = 0; mt < 2; mt++) {
#pragma unroll
        for (int nt = 0; nt < 4; nt++) {
#pragma unroll
            for (int r = 0; r < 4; r++) {
                int row = m0 + wm * 32 + mt * 16 + quad * 4 + r;
                out[(size_t)row * D_DIM + nn[nt]] = acc[mt][nt][r] + bvv[nt];
            }
        }
    }
}

// ---------------------------------------------------------------------------
extern "C" void kernel_launch(void* const* d_in, const int* in_sizes, int n_in,
                              void* d_out, int out_size, void* d_ws, size_t ws_size,
                              hipStream_t stream) {
    const float* q  = (const float*)d_in[0];
    const float* k  = (const float*)d_in[1];
    const float* v  = (const float*)d_in[2];
    const float* Wq = (const float*)d_in[4];
    const float* bq = (const float*)d_in[5];
    const float* Wk = (const float*)d_in[6];
    const float* bk = (const float*)d_in[7];
    const float* Wv = (const float*)d_in[8];
    const float* bv = (const float*)d_in[9];
    const float* Wo = (const float*)d_in[10];
    const float* bo = (const float*)d_in[11];
    float* out = (float*)d_out;

    unsigned short* ws = (unsigned short*)d_ws;
    const size_t WT   = (size_t)D_DIM * D_DIM;     // 1M elems
    const size_t TENS = (size_t)M_ROWS * D_DIM;    // 4M elems
    unsigned short* Wt = ws;                        // 8 MB
    unsigned short* Qp = ws + 4 * WT;               // 8 MB
    unsigned short* Kp = Qp + TENS;                 // 8 MB
    unsigned short* Vt = Kp + TENS;                 // 8 MB
    unsigned short* Xb = Vt + TENS;                 // 24 MB (3 x 8)
    unsigned short* Ap = Xb;                        // aliases Xb[z=0] (dead after gemm_qkv)

    cvt_qkv<<<dim3(2048, 3), 256, 0, stream>>>(q, k, v, Xb);
    transpose_w<<<dim3(16, 16, 4), 256, 0, stream>>>(Wq, Wk, Wv, Wo, Wt);
    gemm_qkv<<<768, 256, 0, stream>>>(Xb, Wt, bq, bk, bv, Qp, Kp, Vt);
    flash8<<<2048, 128, 0, stream>>>(Qp, Kp, Vt, Ap);
    gemm_out<<<512, 256, 0, stream>>>(Ap, Wt + 3 * WT, bo, out);
}

// Round 4
// 265.849 us; speedup vs baseline: 1.0335x; 1.0120x over previous
//
#include <hip/hip_runtime.h>

// MultiHeadAttention: B=2, S=2048, D=1024, H=16, DK=64, causal.
// Inputs fp32, output fp32, intermediates bf16.
// R14: flash9 — software-pipelined flash8: PV lags one step behind QK with
//   double-buffered pw. Iteration = [kc<-kn; prefetch kn; QK(next)+exp+write
//   pw[b^1]; PV(cur) from pw[b]+vf; reload vf=V(next)]. Kills the in-step
//   write->read LDS round-trip and overlaps PV MFMAs with the exp chain.
//   (R13 falsified VALU-bound: -30% VALU instrs gave 0 time change; kernel is
//   stall-bound on the serial QK->exp->write->read->PV chain at ~1.5 resident
//   waves/SIMD.) VGPR must stay <=128.
// ws (56 MB, aliased): Wt 8 | Qp 8 | Kp 8 | Vt 8 | Xb 24 (Ap aliases Xb[0:8])

typedef short v8s  __attribute__((ext_vector_type(8)));
typedef short v4ss __attribute__((ext_vector_type(4)));
typedef float v4f  __attribute__((ext_vector_type(4)));
typedef unsigned int v2u __attribute__((ext_vector_type(2)));

#define S_LEN 2048
#define D_DIM 1024
#define NHEAD 16
#define DK 64
#define M_ROWS 4096

__device__ inline unsigned short f2bf(float f) {
    unsigned x;
    __builtin_memcpy(&x, &f, 4);
    unsigned r = x + 0x7fffu + ((x >> 16) & 1u);  // RNE
    return (unsigned short)(r >> 16);
}

// v_cvt_pk_bf16_f32: D.lo = bf16(lo), D.hi = bf16(hi), RNE
__device__ inline unsigned cvtpk_bf16(float lo, float hi) {
    unsigned d;
    asm("v_cvt_pk_bf16_f32 %0, %1, %2" : "=v"(d) : "v"(lo), "v"(hi));
    return d;
}

__device__ inline void gload_lds16(const void* g, void* l) {
    __builtin_amdgcn_global_load_lds(
        (const __attribute__((address_space(1))) unsigned int*)g,
        (__attribute__((address_space(3))) unsigned int*)l, 16, 0, 0);
}

// ---------------------------------------------------------------------------
// fp32 -> bf16 conversion of q,k,v into Xb[3][4096][1024]. Grid (2048,3) x256.
// ---------------------------------------------------------------------------
__global__ __launch_bounds__(256) void cvt_qkv(
    const float* __restrict__ q, const float* __restrict__ k,
    const float* __restrict__ v, unsigned short* __restrict__ Xb)
{
    const int z = blockIdx.y;
    const float* X = (z == 0) ? q : (z == 1) ? k : v;
    const size_t off = ((size_t)blockIdx.x * 256 + threadIdx.x) * 8;
    float4 f0 = *(const float4*)(X + off);
    float4 f1 = *(const float4*)(X + off + 4);
    v8s p;
    p[0]=(short)f2bf(f0.x); p[1]=(short)f2bf(f0.y); p[2]=(short)f2bf(f0.z); p[3]=(short)f2bf(f0.w);
    p[4]=(short)f2bf(f1.x); p[5]=(short)f2bf(f1.y); p[6]=(short)f2bf(f1.z); p[7]=(short)f2bf(f1.w);
    *(v8s*)(Xb + (size_t)z * M_ROWS * D_DIM + off) = p;
}

// ---------------------------------------------------------------------------
// Weight transpose+cast: W fp32 [k][n] -> Wt bf16 [n][k]. Grid (16,16,4).
// ---------------------------------------------------------------------------
__global__ __launch_bounds__(256) void transpose_w(
    const float* __restrict__ W0, const float* __restrict__ W1,
    const float* __restrict__ W2, const float* __restrict__ W3,
    unsigned short* __restrict__ Wt)
{
    const int z = blockIdx.z;
    const float* W = (z == 0) ? W0 : (z == 1) ? W1 : (z == 2) ? W2 : W3;
    unsigned short* dst = Wt + (size_t)z * D_DIM * D_DIM;

    __shared__ unsigned short t[64][72];
    const int n0 = blockIdx.x * 64, k0 = blockIdx.y * 64;
    const int tid = threadIdx.x;
    const int lr = tid >> 4;
    const int lc = (tid & 15) * 4;

#pragma unroll
    for (int kk = 0; kk < 64; kk += 16) {
        float4 f = *(const float4*)(W + (size_t)(k0 + kk + lr) * D_DIM + n0 + lc);
        t[lc + 0][kk + lr] = f2bf(f.x);
        t[lc + 1][kk + lr] = f2bf(f.y);
        t[lc + 2][kk + lr] = f2bf(f.z);
        t[lc + 3][kk + lr] = f2bf(f.w);
    }
    __syncthreads();
    const int wr = tid >> 2;
    const int wc = (tid & 3) * 16;
    v8s o0, o1;
#pragma unroll
    for (int e = 0; e < 8; e++) { o0[e] = t[wr][wc + e]; o1[e] = t[wr][wc + 8 + e]; }
    *(v8s*)(dst + (size_t)(n0 + wr) * D_DIM + k0 + wc)     = o0;
    *(v8s*)(dst + (size_t)(n0 + wr) * D_DIM + k0 + wc + 8) = o1;
}

// ---------------------------------------------------------------------------
// Fused QKV projection, m97 structure. Flat grid 768, 256 thr, 128x128, BK=32.
// ---------------------------------------------------------------------------
__global__ __launch_bounds__(256) void gemm_qkv(
    const unsigned short* __restrict__ Xb,
    const unsigned short* __restrict__ Wt,
    const float* __restrict__ bq, const float* __restrict__ bk,
    const float* __restrict__ bv,
    unsigned short* __restrict__ Qp, unsigned short* __restrict__ Kp,
    unsigned short* __restrict__ Vt)
{
    const int id   = blockIdx.x;
    const int xcd  = id & 7;
    const int slot = id >> 3;          // 0..95
    const int nblk = slot & 7;
    const int mg   = (slot >> 3) & 3;
    const int z    = slot >> 5;        // 0..2
    const int mblk = mg * 8 + xcd;     // 0..31

    const unsigned short* X = Xb + (size_t)z * M_ROWS * D_DIM;
    const unsigned short* W = Wt + (size_t)z * D_DIM * D_DIM;
    const float* bias = (z == 0) ? bq : (z == 1) ? bk : bv;

    __shared__ unsigned short lds_a[128 * 32];
    __shared__ unsigned short lds_b[128 * 32];

    const int tid  = threadIdx.x;
    const int lane = tid & 63;
    const int wave = tid >> 6;
    const int wm   = wave >> 1;
    const int wn   = wave & 1;
    const int quad = lane >> 4;
    const int col  = lane & 15;
    const int m0   = mblk * 128;
    const int n0   = nblk * 128;

    v4f acc[4][4];
#pragma unroll
    for (int i = 0; i < 4; i++)
#pragma unroll
        for (int j = 0; j < 4; j++)
#pragma unroll
            for (int r = 0; r < 4; r++) acc[i][j][r] = 0.0f;

    const int srow  = wave * 16 + (lane >> 2);
    const int schk  = (lane & 3) * 8;
    unsigned short* la = lds_a + wave * 512 + lane * 8;
    unsigned short* lb = lds_b + wave * 512 + lane * 8;

    for (int k0 = 0; k0 < D_DIM; k0 += 32) {
        __syncthreads();
        gload_lds16(X + (size_t)(m0 + srow) * D_DIM + k0 + schk,        la);
        gload_lds16(X + (size_t)(m0 + 64 + srow) * D_DIM + k0 + schk,   la + 2048);
        gload_lds16(W + (size_t)(n0 + srow) * D_DIM + k0 + schk,        lb);
        gload_lds16(W + (size_t)(n0 + 64 + srow) * D_DIM + k0 + schk,   lb + 2048);
        __syncthreads();

        v8s af[4], bf[4];
#pragma unroll
        for (int mt = 0; mt < 4; mt++)
            af[mt] = *(const v8s*)(lds_a + (wm * 64 + mt * 16 + col) * 32 + quad * 8);
#pragma unroll
        for (int nt = 0; nt < 4; nt++)
            bf[nt] = *(const v8s*)(lds_b + (wn * 64 + nt * 16 + col) * 32 + quad * 8);

#pragma unroll
        for (int mt = 0; mt < 4; mt++)
#pragma unroll
            for (int nt = 0; nt < 4; nt++)
                acc[mt][nt] = __builtin_amdgcn_mfma_f32_16x16x32_bf16(
                    af[mt], bf[nt], acc[mt][nt], 0, 0, 0);
    }

    int   nn[4];
    float bvv[4];
#pragma unroll
    for (int nt = 0; nt < 4; nt++) {
        nn[nt]  = n0 + wn * 64 + nt * 16 + col;
        bvv[nt] = bias[nn[nt]];
    }

    if (z < 2) {
        unsigned short* out = (z == 0) ? Qp : Kp;
#pragma unroll
        for (int mt = 0; mt < 4; mt++) {
#pragma unroll
            for (int nt = 0; nt < 4; nt++) {
                const int h  = nn[nt] >> 6;
                const int dk = nn[nt] & 63;
#pragma unroll
                for (int r = 0; r < 4; r++) {
                    int row = m0 + wm * 64 + mt * 16 + quad * 4 + r;
                    int b   = row >> 11, t = row & 2047;
                    out[(((size_t)(b * NHEAD + h) * S_LEN) + t) * DK + dk] =
                        f2bf(acc[mt][nt][r] + bvv[nt]);
                }
            }
        }
    } else {
#pragma unroll
        for (int mt = 0; mt < 4; mt++) {
#pragma unroll
            for (int nt = 0; nt < 4; nt++) {
                const int h  = nn[nt] >> 6;
                const int dk = nn[nt] & 63;
                int row = m0 + wm * 64 + mt * 16 + quad * 4;
                int b   = row >> 11, t = row & 2047;
                v4ss pk;
#pragma unroll
                for (int r = 0; r < 4; r++) pk[r] = (short)f2bf(acc[mt][nt][r] + bvv[nt]);
                *(v4ss*)(Vt + ((size_t)(b * NHEAD + h) * DK + dk) * S_LEN + t) = pk;
            }
        }
    }
}

// ---------------------------------------------------------------------------
// Flash attention v9 — flash8 + one-step software pipeline.
// 2 waves/block, even/odd KV steps; swapped QK^T P-pack; double-buffered pw.
// Iteration: [kc<-kn; prefetch kn=K(next+2); QK(next)+exp+write pw[b^1];
//            PV(cur) from pw[b],vf; vf=load V(next); b^=1].
// PV reads LDS written a full iteration earlier -> no write->read stall;
// PV MFMAs independent of the concurrent QK/exp chain.
// Grid: 2048 blocks x 128 thr. Fixed-CM deferred softmax; 1-round combine.
// ---------------------------------------------------------------------------
__global__ __launch_bounds__(128) void flash9(
    const unsigned short* __restrict__ Qp,
    const unsigned short* __restrict__ Kp,
    const unsigned short* __restrict__ Vt,
    unsigned short* __restrict__ Op)
{
    // pw: 2 waves x 2 bufs x [32][72] shorts = 18432 B | combine 64x34 f32 = 8704 B
    __shared__ __align__(16) unsigned char smem[18432];

    const int tid  = threadIdx.x;
    const int wave = tid >> 6;
    const int lane = tid & 63;
    const int quad = lane >> 4;
    const int col  = lane & 15;

    unsigned short* pwb = (unsigned short*)smem + wave * 2 * (32 * 72);

    const int i   = blockIdx.x;
    const int xcd = i & 7;
    const int j   = i >> 3;
    const int bh  = xcd * 4 + (j & 3);
    const int q32 = 63 - (j >> 2);
    const int r0  = q32 * 32;

    const unsigned short* Qh = Qp + (size_t)bh * S_LEN * DK;
    const unsigned short* Kh = Kp + (size_t)bh * S_LEN * DK;
    const unsigned short* Vh = Vt + (size_t)bh * DK * S_LEN;

    v8s qf[2][2];
#pragma unroll
    for (int mt = 0; mt < 2; mt++)
#pragma unroll
        for (int c = 0; c < 2; c++)
            qf[mt][c] = *(const v8s*)(Qh + (size_t)(r0 + mt * 16 + col) * DK + c * 32 + quad * 8);

    float lpart[2] = {0.f, 0.f};
    v4f acc_o[2][4];
#pragma unroll
    for (int mt = 0; mt < 2; mt++)
#pragma unroll
        for (int nt = 0; nt < 4; nt++)
#pragma unroll
            for (int r = 0; r < 4; r++) acc_o[mt][nt][r] = 0.0f;

    const float CS = 0.18033688f;   // 0.125*log2(e)
    const float CM = 28.8539008f;   // 20*log2(e)

    const int nsteps = (q32 >> 1) + 1;

    v8s kc[2][4], kn[2][4], vf[2][4];

    // QK + exp + pack-write for step STEP into buffer pd
    auto qk_step = [&](int STEP, unsigned short* pd) {
        const int kv0 = STEP * 64;
#pragma unroll
        for (int mt = 0; mt < 2; mt++) {
            v4f s[4];
#pragma unroll
            for (int nt = 0; nt < 4; nt++) {
#pragma unroll
                for (int r = 0; r < 4; r++) s[nt][r] = 0.0f;
#pragma unroll
                for (int c = 0; c < 2; c++)
                    s[nt] = __builtin_amdgcn_mfma_f32_16x16x32_bf16(kc[c][nt], qf[mt][c], s[nt], 0, 0, 0);
            }
            const int rbase = r0 + mt * 16;
            float lp = 0.f;
            if (kv0 + 64 > rbase) {
#pragma unroll
                for (int nt = 0; nt < 4; nt++) {
#pragma unroll
                    for (int r = 0; r < 4; r++) {
                        float p = __builtin_amdgcn_exp2f(fmaf(s[nt][r], CS, -CM));
                        if (kv0 + nt * 16 + quad * 4 + r > rbase + col) p = 0.0f;
                        s[nt][r] = p;
                        lp += p;
                    }
                }
            } else {
#pragma unroll
                for (int nt = 0; nt < 4; nt++) {
#pragma unroll
                    for (int r = 0; r < 4; r++) {
                        float p = __builtin_amdgcn_exp2f(fmaf(s[nt][r], CS, -CM));
                        s[nt][r] = p;
                        lp += p;
                    }
                }
            }
            lpart[mt] += lp;
#pragma unroll
            for (int nt = 0; nt < 4; nt++) {
                unsigned u0 = cvtpk_bf16(s[nt][0], s[nt][1]);
                unsigned u1 = cvtpk_bf16(s[nt][2], s[nt][3]);
                v2u w; w[0] = u0; w[1] = u1;
                *(v2u*)(pd + (mt * 16 + col) * 72 + nt * 16 + quad * 4) = w;
            }
        }
    };

    // PV accumulate from buffer ps using current vf
    auto pv_step = [&](const unsigned short* ps) {
#pragma unroll
        for (int mt = 0; mt < 2; mt++) {
#pragma unroll
            for (int c = 0; c < 2; c++) {
                v8s af = *(const v8s*)(ps + (mt * 16 + col) * 72 + c * 32 + quad * 8);
#pragma unroll
                for (int nt = 0; nt < 4; nt++)
                    acc_o[mt][nt] = __builtin_amdgcn_mfma_f32_16x16x32_bf16(af, vf[c][nt], acc_o[mt][nt], 0, 0, 0);
            }
        }
    };

    int st = wave;
    if (st < nsteps) {
        // load kc = K(st), vf = V(st)
#pragma unroll
        for (int c = 0; c < 2; c++)
#pragma unroll
            for (int nt = 0; nt < 4; nt++) {
                kc[c][nt] = *(const v8s*)(Kh + (size_t)(st * 64 + nt * 16 + col) * DK + c * 32 + quad * 8);
                vf[c][nt] = *(const v8s*)(Vh + (size_t)(nt * 16 + col) * S_LEN + st * 64 + c * 32 + quad * 8);
            }

        qk_step(st, pwb);            // buffer 0
        int b = 0;

        // prefetch kn = K(st+2) (clamped)
        {
            const int p = (st + 2 < nsteps) ? st + 2 : st;
#pragma unroll
            for (int c = 0; c < 2; c++)
#pragma unroll
                for (int nt = 0; nt < 4; nt++)
                    kn[c][nt] = *(const v8s*)(Kh + (size_t)(p * 64 + nt * 16 + col) * DK + c * 32 + quad * 8);
        }

        while (st + 2 < nsteps) {
            const int nx = st + 2;
            // kc <- kn; issue next prefetch
#pragma unroll
            for (int c = 0; c < 2; c++)
#pragma unroll
                for (int nt = 0; nt < 4; nt++)
                    kc[c][nt] = kn[c][nt];
            {
                const int p2 = (nx + 2 < nsteps) ? nx + 2 : nx;
#pragma unroll
                for (int c = 0; c < 2; c++)
#pragma unroll
                    for (int nt = 0; nt < 4; nt++)
                        kn[c][nt] = *(const v8s*)(Kh + (size_t)(p2 * 64 + nt * 16 + col) * DK + c * 32 + quad * 8);
            }

            qk_step(nx, pwb + (b ^ 1) * 2304);   // write next P
            pv_step(pwb + b * 2304);             // consume prev P with vf=V(st)

            // reload vf = V(nx) for next iteration's PV
#pragma unroll
            for (int c = 0; c < 2; c++)
#pragma unroll
                for (int nt = 0; nt < 4; nt++)
                    vf[c][nt] = *(const v8s*)(Vh + (size_t)(nt * 16 + col) * S_LEN + nx * 64 + c * 32 + quad * 8);

            b ^= 1;
            st = nx;
        }

        pv_step(pwb + b * 2304);                 // final PV
    }

    // per-wave l: reduce across quads (kv partitions); all lanes -> l[q=col]
#pragma unroll
    for (int mt = 0; mt < 2; mt++) {
        lpart[mt] += __shfl_xor(lpart[mt], 16);
        lpart[mt] += __shfl_xor(lpart[mt], 32);
    }

    // ---- cross-wave combine (linear: fixed-max deferred softmax) ----
    float* comb = (float*)smem;
    __syncthreads();                      // pw use complete; smem reusable
    if (wave == 1) {
        float* dst = comb + lane * 34;
#pragma unroll
        for (int mt = 0; mt < 2; mt++)
#pragma unroll
            for (int nt = 0; nt < 4; nt++)
                *(v4f*)(dst + (mt * 4 + nt) * 4) = acc_o[mt][nt];
        dst[32] = lpart[0];
        dst[33] = lpart[1];
    }
    __syncthreads();
    if (wave != 0) return;

    {
        const float* src = comb + lane * 34;
#pragma unroll
        for (int mt = 0; mt < 2; mt++)
#pragma unroll
            for (int nt = 0; nt < 4; nt++) {
                v4f o = *(const v4f*)(src + (mt * 4 + nt) * 4);
#pragma unroll
                for (int r = 0; r < 4; r++) acc_o[mt][nt][r] += o[r];
            }
        lpart[0] += src[32];
        lpart[1] += src[33];
    }

    // normalize: invert, redistribute l[q=col] to lanes needing rows quad*4+r
    lpart[0] = 1.0f / lpart[0];
    lpart[1] = 1.0f / lpart[1];
    float li[2][4];
#pragma unroll
    for (int mt = 0; mt < 2; mt++)
#pragma unroll
        for (int r = 0; r < 4; r++)
            li[mt][r] = __shfl(lpart[mt], quad * 4 + r);

#pragma unroll
    for (int mt = 0; mt < 2; mt++) {
#pragma unroll
        for (int nt = 0; nt < 4; nt++) {
#pragma unroll
            for (int r = 0; r < 4; r++) {
                size_t addr = ((size_t)bh * S_LEN + r0 + mt * 16 + quad * 4 + r) * DK + nt * 16 + col;
                Op[addr] = f2bf(acc_o[mt][nt][r] * li[mt][r]);
            }
        }
    }
}

// ---------------------------------------------------------------------------
// Final projection, m97 staging. Flat 512 blocks, 64x128 tiles.
// ---------------------------------------------------------------------------
__global__ __launch_bounds__(256) void gemm_out(
    const unsigned short* __restrict__ Ap,
    const unsigned short* __restrict__ Wot,
    const float* __restrict__ bo,
    float* __restrict__ out)
{
    __shared__ unsigned short lds_a[64 * 32];
    __shared__ unsigned short lds_b[128 * 32];

    const int id   = blockIdx.x;
    const int xcd  = id & 7;
    const int slot = id >> 3;
    const int nblk = slot & 7;
    const int mg   = slot >> 3;
    const int mblk = mg * 8 + xcd;   // 0..63

    const int tid  = threadIdx.x;
    const int lane = tid & 63;
    const int wave = tid >> 6;
    const int wm   = wave >> 1;
    const int wn   = wave & 1;
    const int quad = lane >> 4;
    const int col  = lane & 15;
    const int m0   = mblk * 64;
    const int n0   = nblk * 128;

    v4f acc[2][4];
#pragma unroll
    for (int i = 0; i < 2; i++)
#pragma unroll
        for (int j = 0; j < 4; j++)
#pragma unroll
            for (int r = 0; r < 4; r++) acc[i][j][r] = 0.0f;

    const int srow = wave * 16 + (lane >> 2);
    const int schk = (lane & 3) * 8;
    unsigned short* la = lds_a + wave * 512 + lane * 8;
    unsigned short* lb = lds_b + wave * 512 + lane * 8;

    const int tokA = m0 + srow;
    const int bbA  = tokA >> 11, ttA = tokA & 2047;

    for (int k0 = 0; k0 < D_DIM; k0 += 32) {
        const int h = k0 >> 6;
        const int dk = (k0 & 63) + schk;
        __syncthreads();
        gload_lds16(Ap + ((size_t)(bbA * NHEAD + h) * S_LEN + ttA) * DK + dk,  la);
        gload_lds16(Wot + (size_t)(n0 + srow) * D_DIM + k0 + schk,             lb);
        gload_lds16(Wot + (size_t)(n0 + 64 + srow) * D_DIM + k0 + schk,        lb + 2048);
        __syncthreads();

        v8s af[2], bf[4];
#pragma unroll
        for (int mt = 0; mt < 2; mt++)
            af[mt] = *(const v8s*)(lds_a + (wm * 32 + mt * 16 + col) * 32 + quad * 8);
#pragma unroll
        for (int nt = 0; nt < 4; nt++)
            bf[nt] = *(const v8s*)(lds_b + (wn * 64 + nt * 16 + col) * 32 + quad * 8);

#pragma unroll
        for (int mt = 0; mt < 2; mt++)
#pragma unroll
            for (int nt = 0; nt < 4; nt++)
                acc[mt][nt] = __builtin_amdgcn_mfma_f32_16x16x32_bf16(
                    af[mt], bf[nt], acc[mt][nt], 0, 0, 0);
    }

    float bvv[4];
    int   nn[4];
#pragma unroll
    for (int nt = 0; nt < 4; nt++) {
        nn[nt]  = n0 + wn * 64 + nt * 16 + col;
        bvv[nt] = bo[nn[nt]];
    }

#pragma unroll
    for (int mt = 0; mt < 2; mt++) {
#pragma unroll
        for (int nt = 0; nt < 4; nt++) {
#pragma unroll
            for (int r = 0; r < 4; r++) {
                int row = m0 + wm * 32 + mt * 16 + quad * 4 + r;
                out[(size_t)row * D_DIM + nn[nt]] = acc[mt][nt][r] + bvv[nt];
            }
        }
    }
}

// ---------------------------------------------------------------------------
extern "C" void kernel_launch(void* const* d_in, const int* in_sizes, int n_in,
                              void* d_out, int out_size, void* d_ws, size_t ws_size,
                              hipStream_t stream) {
    const float* q  = (const float*)d_in[0];
    const float* k  = (const float*)d_in[1];
    const float* v  = (const float*)d_in[2];
    const float* Wq = (const float*)d_in[4];
    const float* bq = (const float*)d_in[5];
    const float* Wk = (const float*)d_in[6];
    const float* bk = (const float*)d_in[7];
    const float* Wv = (const float*)d_in[8];
    const float* bv = (const float*)d_in[9];
    const float* Wo = (const float*)d_in[10];
    const float* bo = (const float*)d_in[11];
    float* out = (float*)d_out;

    unsigned short* ws = (unsigned short*)d_ws;
    const size_t WT   = (size_t)D_DIM * D_DIM;     // 1M elems
    const size_t TENS = (size_t)M_ROWS * D_DIM;    // 4M elems
    unsigned short* Wt = ws;                        // 8 MB
    unsigned short* Qp = ws + 4 * WT;               // 8 MB
    unsigned short* Kp = Qp + TENS;                 // 8 MB
    unsigned short* Vt = Kp + TENS;                 // 8 MB
    unsigned short* Xb = Vt + TENS;                 // 24 MB (3 x 8)
    unsigned short* Ap = Xb;                        // aliases Xb[z=0] (dead after gemm_qkv)

    cvt_qkv<<<dim3(2048, 3), 256, 0, stream>>>(q, k, v, Xb);
    transpose_w<<<dim3(16, 16, 4), 256, 0, stream>>>(Wq, Wk, Wv, Wo, Wt);
    gemm_qkv<<<768, 256, 0, stream>>>(Xb, Wt, bq, bk, bv, Qp, Kp, Vt);
    flash9<<<2048, 128, 0, stream>>>(Qp, Kp, Vt, Ap);
    gemm_out<<<512, 256, 0, stream>>>(Ap, Wt + 3 * WT, bo, out);
}